// Round 1
// baseline (3144.396 us; speedup 1.0000x reference)
//
#include <hip/hip_runtime.h>

// ---------------------------------------------------------------------------
// ParamMemAdam: hs features collapse to a 64-entry token table (token-wise
// computation, no position dependence). Then 256 independent sequential Adam
// scans (3069 steps) -> one block per batch element, params+moments in regs.
// ---------------------------------------------------------------------------

__device__ __forceinline__ void adam_upd(float& p, float& m1, float& m2,
                                         float g, float c2inv, float nls)
{
  m1 = fmaf(0.9f,  m1, 0.1f   * g);
  m2 = fmaf(0.999f, m2, 0.001f * (g * g));
  float den = __builtin_amdgcn_sqrtf(m2 * c2inv) + 1e-8f;
  p = fmaf(nls * m1, __builtin_amdgcn_rcpf(den), p);
}

// ---- prep: hs_table[v][j] = LN(e_v + FF(e_v)) for the 64 possible tokens ----
__global__ void prep_kernel(const float* __restrict__ emb,
                            const float* __restrict__ ffw1, const float* __restrict__ ffb1,
                            const float* __restrict__ ffw2, const float* __restrict__ ffb2,
                            const float* __restrict__ lng,  const float* __restrict__ lnb,
                            float* __restrict__ hs_out)
{
  const int v = blockIdx.x;   // token id
  const int t = threadIdx.x;  // 128 threads
  __shared__ float e[64];
  __shared__ float r[128];
  if (t < 64) e[t] = emb[v * 64 + t];
  __syncthreads();
  {
    float s = ffb1[t];
    const float* wrow = ffw1 + t * 64;
#pragma unroll 8
    for (int m = 0; m < 64; ++m) s = fmaf(wrow[m], e[m], s);
    r[t] = fmaxf(s, 0.f);
  }
  __syncthreads();
  if (t < 64) {
    float s = ffb2[t];
    const float* wrow = ffw2 + t * 128;
#pragma unroll 8
    for (int o = 0; o < 128; ++o) s = fmaf(wrow[o], r[o], s);
    float x = e[t] + s;
    float mu = x;
    for (int m = 1; m < 64; m <<= 1) mu += __shfl_xor(mu, m, 64);
    mu *= (1.f / 64.f);
    float dv = x - mu;
    float var = dv * dv;
    for (int m = 1; m < 64; m <<= 1) var += __shfl_xor(var, m, 64);
    var *= (1.f / 64.f);
    float hs = dv / sqrtf(var + 1e-5f);
    hs_out[v * 64 + t] = hs * lng[t] + lnb[t];
  }
}

// ---- main scan: one block per batch element -------------------------------
// thread t: w1 row i1=t>>3, cols j0=(t&7)*8..+8 ; w2 rows p0=2*(t>>3),p0+1,
// cols c0=(t&7)*4..+4. b1[i1], b2[p0..p0+1] replicated across the 8-lane group.
__global__ __launch_bounds__(256)
void scan_kernel(const int* __restrict__ seq, const float* __restrict__ hs_tab,
                 const float* __restrict__ fc1w, const float* __restrict__ fc1b,
                 const float* __restrict__ fc2w, const float* __restrict__ fc2b,
                 const float* __restrict__ outw, const float* __restrict__ outb,
                 float* __restrict__ out)
{
  const int b    = blockIdx.x;
  const int t    = threadIdx.x;
  const int lane = t & 63;
  const int wv   = t >> 6;
  const int i1   = t >> 3;
  const int j0   = (t & 7) << 3;
  const int p0   = i1 << 1;
  const int c0   = (t & 7) << 2;
  const int sub  = t & 7;

  __shared__ __align__(16) float hs[4096];   // token table 64x64
  __shared__ __align__(16) int   sq[2048];   // this batch's token ids
  __shared__ __align__(16) float h_s[32];    // hidden vector
  __shared__ __align__(16) float dhp[4][32]; // per-wave dh partials
  __shared__ __align__(16) float ctx[64];    // final context

  for (int i = t; i < 1024; i += 256)
    ((float4*)hs)[i] = ((const float4*)hs_tab)[i];
  {
    const int4* sg = (const int4*)(seq + (long long)b * 2048);
    for (int i = t; i < 512; i += 256) ((int4*)sq)[i] = sg[i];
  }

  float w1r[8], m1a[8], m2a[8];
  float w2r[8], m1b[8], m2b[8];
#pragma unroll
  for (int jj = 0; jj < 8; ++jj) {
    w1r[jj] = fc1w[i1 * 64 + j0 + jj];
    m1a[jj] = 0.f; m2a[jj] = 0.f;
  }
#pragma unroll
  for (int z = 0; z < 8; ++z) {
    w2r[z] = fc2w[(p0 + (z >> 2)) * 32 + c0 + (z & 3)];
    m1b[z] = 0.f; m2b[z] = 0.f;
  }
  float b1v  = fc1b[i1];     float m1c = 0.f, m2c = 0.f;
  float b2v0 = fc2b[p0];     float m1d0 = 0.f, m2d0 = 0.f;
  float b2v1 = fc2b[p0 + 1]; float m1d1 = 0.f, m2d1 = 0.f;

  __syncthreads();

  double pb1 = 1.0, pb2 = 1.0;
  int jm = 1;

  // ---- prologue: phase A of step 0
  float kk[8], hv, v0, v1;
  {
    const int ka = sq[0], vb = sq[1];
    const float4 k0 = *(const float4*)(hs + ka * 64 + j0);
    const float4 k1 = *(const float4*)(hs + ka * 64 + j0 + 4);
    kk[0]=k0.x; kk[1]=k0.y; kk[2]=k0.z; kk[3]=k0.w;
    kk[4]=k1.x; kk[5]=k1.y; kk[6]=k1.z; kk[7]=k1.w;
    v0 = hs[vb * 64 + p0];
    v1 = hs[vb * 64 + p0 + 1];
    float pa = 0.f;
#pragma unroll
    for (int jj = 0; jj < 8; ++jj) pa = fmaf(w1r[jj], kk[jj], pa);
    pa += __shfl_xor(pa, 1, 64);
    pa += __shfl_xor(pa, 2, 64);
    pa += __shfl_xor(pa, 4, 64);
    hv = fmaxf(pa + b1v, 0.f);
    if (sub == 1) h_s[i1] = hv;
  }
  __syncthreads();

  for (int step = 0; step < 3069; ++step) {
    pb1 *= 0.9; pb2 *= 0.999;
    const float c1inv = __builtin_amdgcn_rcpf((float)(1.0 - pb1));
    const float c2inv = __builtin_amdgcn_rcpf((float)(1.0 - pb2));
    const float nls   = -0.05f * c1inv;

    // ---- B: pred = w2 h + b2 ; d = (2/64)(pred - v)   (all lanes get d)
    float hh[4];
    {
      const float4 h4 = *(const float4*)(h_s + c0);
      hh[0]=h4.x; hh[1]=h4.y; hh[2]=h4.z; hh[3]=h4.w;
    }
    float q0 = 0.f, q1 = 0.f;
#pragma unroll
    for (int ii = 0; ii < 4; ++ii) {
      q0 = fmaf(w2r[ii],     hh[ii], q0);
      q1 = fmaf(w2r[4 + ii], hh[ii], q1);
    }
    q0 += __shfl_xor(q0, 1, 64);  q1 += __shfl_xor(q1, 1, 64);
    q0 += __shfl_xor(q0, 2, 64);  q1 += __shfl_xor(q1, 2, 64);
    q0 += __shfl_xor(q0, 4, 64);  q1 += __shfl_xor(q1, 4, 64);
    const float dd0 = 0.03125f * (q0 + b2v0 - v0);
    const float dd1 = 0.03125f * (q1 + b2v1 - v1);

    // ---- C: dh partials with OLD w2
    float dp[4];
#pragma unroll
    for (int ii = 0; ii < 4; ++ii)
      dp[ii] = fmaf(w2r[4 + ii], dd1, w2r[ii] * dd0);

    // ---- w2/b2 Adam (g doesn't involve w2; dp already captured old w2)
#pragma unroll
    for (int ii = 0; ii < 4; ++ii) {
      adam_upd(w2r[ii],     m1b[ii],     m2b[ii],     dd0 * hh[ii], c2inv, nls);
      adam_upd(w2r[4 + ii], m1b[4 + ii], m2b[4 + ii], dd1 * hh[ii], c2inv, nls);
    }
    adam_upd(b2v0, m1d0, m2d0, dd0, c2inv, nls);
    adam_upd(b2v1, m1d1, m2d1, dd1, c2inv, nls);

    // ---- C reduce: within-wave over the 8 row-pair groups
#pragma unroll
    for (int ii = 0; ii < 4; ++ii) {
      dp[ii] += __shfl_xor(dp[ii], 8, 64);
      dp[ii] += __shfl_xor(dp[ii], 16, 64);
      dp[ii] += __shfl_xor(dp[ii], 32, 64);
    }
    if (lane < 8)
      *(float4*)(&dhp[wv][(lane & 7) << 2]) = make_float4(dp[0], dp[1], dp[2], dp[3]);
    __syncthreads();

    // ---- D: dh + w1/b1 Adam
    const float dhsum = (dhp[0][i1] + dhp[1][i1]) + (dhp[2][i1] + dhp[3][i1]);
    const float dh = (hv > 0.f) ? dhsum : 0.f;
#pragma unroll
    for (int jj = 0; jj < 8; ++jj)
      adam_upd(w1r[jj], m1a[jj], m2a[jj], dh * kk[jj], c2inv, nls);
    adam_upd(b1v, m1c, m2c, dh, c2inv, nls);

    // ---- A of next step (or the final query on the last iteration)
    {
      int ka, vb;
      if (step < 3068) {
        ka = sq[2 * jm]; vb = sq[2 * jm + 1];
        jm = (jm == 1022) ? 0 : jm + 1;
      } else {
        ka = sq[2047]; vb = 0;  // query token; v unused afterwards
      }
      const float4 k0 = *(const float4*)(hs + ka * 64 + j0);
      const float4 k1 = *(const float4*)(hs + ka * 64 + j0 + 4);
      kk[0]=k0.x; kk[1]=k0.y; kk[2]=k0.z; kk[3]=k0.w;
      kk[4]=k1.x; kk[5]=k1.y; kk[6]=k1.z; kk[7]=k1.w;
      v0 = hs[vb * 64 + p0];
      v1 = hs[vb * 64 + p0 + 1];
      float pa = 0.f;
#pragma unroll
      for (int jj = 0; jj < 8; ++jj) pa = fmaf(w1r[jj], kk[jj], pa);
      pa += __shfl_xor(pa, 1, 64);
      pa += __shfl_xor(pa, 2, 64);
      pa += __shfl_xor(pa, 4, 64);
      hv = fmaxf(pa + b1v, 0.f);
      if (sub == 1) h_s[i1] = hv;
    }
    __syncthreads();
  }

  // ---- epilogue: ctx = w2 h_q + b2 (no relu on output layer)
  {
    float hh[4];
    const float4 h4 = *(const float4*)(h_s + c0);
    hh[0]=h4.x; hh[1]=h4.y; hh[2]=h4.z; hh[3]=h4.w;
    float q0 = 0.f, q1 = 0.f;
#pragma unroll
    for (int ii = 0; ii < 4; ++ii) {
      q0 = fmaf(w2r[ii],     hh[ii], q0);
      q1 = fmaf(w2r[4 + ii], hh[ii], q1);
    }
    q0 += __shfl_xor(q0, 1, 64);  q1 += __shfl_xor(q1, 1, 64);
    q0 += __shfl_xor(q0, 2, 64);  q1 += __shfl_xor(q1, 2, 64);
    q0 += __shfl_xor(q0, 4, 64);  q1 += __shfl_xor(q1, 4, 64);
    if (sub == 2) { ctx[p0] = q0 + b2v0; ctx[p0 + 1] = q1 + b2v1; }
  }
  __syncthreads();

  // ---- output projection: out[b][u] = out_b[u] + sum_p out_w[u][p]*ctx[p]
  if (t < 64) {
    float acc = outb[t];
    const float* wrow = outw + t * 64;
#pragma unroll 8
    for (int p = 0; p < 64; ++p) acc = fmaf(wrow[p], ctx[p], acc);
    out[(long long)b * 64 + t] = acc;
  }
}

extern "C" void kernel_launch(void* const* d_in, const int* in_sizes, int n_in,
                              void* d_out, int out_size, void* d_ws, size_t ws_size,
                              hipStream_t stream) {
  const int*   seq  = (const int*)  d_in[0];
  const float* emb  = (const float*)d_in[1];
  const float* ffw1 = (const float*)d_in[2];
  const float* ffb1 = (const float*)d_in[3];
  const float* ffw2 = (const float*)d_in[4];
  const float* ffb2 = (const float*)d_in[5];
  const float* lng  = (const float*)d_in[6];
  const float* lnb  = (const float*)d_in[7];
  const float* fc1w = (const float*)d_in[8];
  const float* fc1b = (const float*)d_in[9];
  const float* fc2w = (const float*)d_in[10];
  const float* fc2b = (const float*)d_in[11];
  const float* outw = (const float*)d_in[12];
  const float* outb = (const float*)d_in[13];
  float* out    = (float*)d_out;
  float* hs_tab = (float*)d_ws;   // 64*64 floats = 16 KB

  prep_kernel<<<64, 128, 0, stream>>>(emb, ffw1, ffb1, ffw2, ffb2, lng, lnb, hs_tab);
  scan_kernel<<<256, 256, 0, stream>>>(seq, hs_tab, fc1w, fc1b, fc2w, fc2b,
                                       outw, outb, out);
}

// Round 3
// 3122.950 us; speedup vs baseline: 1.0069x; 1.0069x over previous
//
#include <hip/hip_runtime.h>

// ---------------------------------------------------------------------------
// ParamMemAdam: hs features collapse to a 64-entry token table. 256
// independent sequential Adam scans (3069 steps) -> one block per batch
// element, params+moments in regs.
// R3: Adam math bit-identical to R1 (validated trajectory). Schedule-only
// changes: k/v prefetch one step ahead, transposed dhp (b128 read), and
// per-step (nls, c2inv) precomputed by a 1-thread kernel with the identical
// f64/rcp op sequence, staged in LDS, prefetched one step ahead.
// ---------------------------------------------------------------------------

// Bit-identical to R1's update.
__device__ __forceinline__ void adam_upd(float& p, float& m1, float& m2,
                                         float g, float c2inv, float nls)
{
  m1 = fmaf(0.9f,  m1, 0.1f   * g);
  m2 = fmaf(0.999f, m2, 0.001f * (g * g));
  float den = __builtin_amdgcn_sqrtf(m2 * c2inv) + 1e-8f;
  p = fmaf(nls * m1, __builtin_amdgcn_rcpf(den), p);
}

// ---- prep: hs_table[v][j] = LN(e_v + FF(e_v)) for the 64 possible tokens ----
__global__ void prep_kernel(const float* __restrict__ emb,
                            const float* __restrict__ ffw1, const float* __restrict__ ffb1,
                            const float* __restrict__ ffw2, const float* __restrict__ ffb2,
                            const float* __restrict__ lng,  const float* __restrict__ lnb,
                            float* __restrict__ hs_out)
{
  const int v = blockIdx.x;   // token id
  const int t = threadIdx.x;  // 128 threads
  __shared__ float e[64];
  __shared__ float r[128];
  if (t < 64) e[t] = emb[v * 64 + t];
  __syncthreads();
  {
    float s = ffb1[t];
    const float* wrow = ffw1 + t * 64;
#pragma unroll 8
    for (int m = 0; m < 64; ++m) s = fmaf(wrow[m], e[m], s);
    r[t] = fmaxf(s, 0.f);
  }
  __syncthreads();
  if (t < 64) {
    float s = ffb2[t];
    const float* wrow = ffw2 + t * 128;
#pragma unroll 8
    for (int o = 0; o < 128; ++o) s = fmaf(wrow[o], r[o], s);
    float x = e[t] + s;
    float mu = x;
    for (int m = 1; m < 64; m <<= 1) mu += __shfl_xor(mu, m, 64);
    mu *= (1.f / 64.f);
    float dv = x - mu;
    float var = dv * dv;
    for (int m = 1; m < 64; m <<= 1) var += __shfl_xor(var, m, 64);
    var *= (1.f / 64.f);
    float hs = dv / sqrtf(var + 1e-5f);
    hs_out[v * 64 + t] = hs * lng[t] + lnb[t];
  }
}

// ---- per-step Adam scale table: EXACT op sequence of the R1 in-loop code ----
__global__ __launch_bounds__(64)
void table_kernel(float* __restrict__ tab)   // tab[2n] = nls, tab[2n+1] = c2inv
{
  if (threadIdx.x != 0) return;
  double pb1 = 1.0, pb2 = 1.0;
  for (int n = 0; n < 3069; ++n) {
    pb1 *= 0.9; pb2 *= 0.999;
    float c1inv = __builtin_amdgcn_rcpf((float)(1.0 - pb1));
    float c2inv = __builtin_amdgcn_rcpf((float)(1.0 - pb2));
    tab[2 * n]     = -0.05f * c1inv;
    tab[2 * n + 1] = c2inv;
  }
}

// ---- main scan: one block per batch element -------------------------------
// thread t: w1 row i1=t>>3, cols j0=(t&7)*8..+8 ; w2 rows p0=2*i1,p0+1,
// cols c0=(t&7)*4..+4. b1[i1], b2[p0..p0+1] replicated across the 8-lane group.
__global__ __launch_bounds__(256)
void scan_kernel(const int* __restrict__ seq, const float* __restrict__ hs_tab,
                 const float* __restrict__ tab_g,
                 const float* __restrict__ fc1w, const float* __restrict__ fc1b,
                 const float* __restrict__ fc2w, const float* __restrict__ fc2b,
                 const float* __restrict__ outw, const float* __restrict__ outb,
                 float* __restrict__ out)
{
  const int b    = blockIdx.x;
  const int t    = threadIdx.x;
  const int lane = t & 63;
  const int wv   = t >> 6;
  const int i1   = t >> 3;
  const int j0   = (t & 7) << 3;
  const int p0   = i1 << 1;
  const int c0   = (t & 7) << 2;
  const int sub  = t & 7;

  __shared__ __align__(16) float hs[4096];    // token table 64x64
  __shared__ __align__(16) int   sq[2048];    // this batch's token ids
  __shared__ __align__(16) float tabs[6144];  // (nls, c2inv) per step
  __shared__ __align__(16) float h_s[32];     // hidden vector
  __shared__ __align__(16) float dhp[32][4];  // dh partials, [i1][wave]
  __shared__ __align__(16) float ctx[64];     // final context

  for (int i = t; i < 1024; i += 256)
    ((float4*)hs)[i] = ((const float4*)hs_tab)[i];
  {
    const int4* sg = (const int4*)(seq + (long long)b * 2048);
    for (int i = t; i < 512; i += 256) ((int4*)sq)[i] = sg[i];
  }
  for (int i = t; i < 1536; i += 256)
    ((float4*)tabs)[i] = ((const float4*)tab_g)[i];

  float w1r[8], m1a[8], m2a[8];
  float w2r[8], m1b[8], m2b[8];
#pragma unroll
  for (int jj = 0; jj < 8; ++jj) {
    w1r[jj] = fc1w[i1 * 64 + j0 + jj];
    m1a[jj] = 0.f; m2a[jj] = 0.f;
  }
#pragma unroll
  for (int z = 0; z < 8; ++z) {
    w2r[z] = fc2w[(p0 + (z >> 2)) * 32 + c0 + (z & 3)];
    m1b[z] = 0.f; m2b[z] = 0.f;
  }
  float b1v  = fc1b[i1];     float m1c = 0.f, m2c = 0.f;
  float b2v0 = fc2b[p0];     float m1d0 = 0.f, m2d0 = 0.f;
  float b2v1 = fc2b[p0 + 1]; float m1d1 = 0.f, m2d1 = 0.f;

  __syncthreads();

  int jm = 1;

  // ---- prologue: step-0 scales, load (k0,v0), phase A of step 0
  float nls_c  = tabs[0];
  float c2i_c  = tabs[1];
  float kk[8], hv, v0, v1;
  {
    const int ka = sq[0], vb = sq[1];
    const float4 k0 = *(const float4*)(hs + ka * 64 + j0);
    const float4 k1 = *(const float4*)(hs + ka * 64 + j0 + 4);
    kk[0]=k0.x; kk[1]=k0.y; kk[2]=k0.z; kk[3]=k0.w;
    kk[4]=k1.x; kk[5]=k1.y; kk[6]=k1.z; kk[7]=k1.w;
    v0 = hs[vb * 64 + p0];
    v1 = hs[vb * 64 + p0 + 1];
    float pa = 0.f;
#pragma unroll
    for (int jj = 0; jj < 8; ++jj) pa = fmaf(w1r[jj], kk[jj], pa);
    pa += __shfl_xor(pa, 1, 64);
    pa += __shfl_xor(pa, 2, 64);
    pa += __shfl_xor(pa, 4, 64);
    hv = fmaxf(pa + b1v, 0.f);
    if (sub == 1) h_s[i1] = hv;
  }
  __syncthreads();

  for (int step = 0; step < 3069; ++step) {
    // ---- prefetch next step's scales (uniform LDS broadcast)
    const int ni = (step < 3068) ? (step + 1) : 3068;
    const float nls_n = tabs[2 * ni];
    const float c2i_n = tabs[2 * ni + 1];
    const float nls   = nls_c;
    const float c2inv = c2i_c;

    // ---- prefetch (k,v) for step+1 (or query on last step): the sq->hs
    // dependent LDS chain hides under B/C/Adam below.
    float kn[8], v0n, v1n;
    {
      int ka, vb;
      if (step < 3068) {
        ka = sq[2 * jm]; vb = sq[2 * jm + 1];
        jm = (jm == 1022) ? 0 : jm + 1;
      } else {
        ka = sq[2047]; vb = 0;  // query token; v unused afterwards
      }
      const float4 k0 = *(const float4*)(hs + ka * 64 + j0);
      const float4 k1 = *(const float4*)(hs + ka * 64 + j0 + 4);
      kn[0]=k0.x; kn[1]=k0.y; kn[2]=k0.z; kn[3]=k0.w;
      kn[4]=k1.x; kn[5]=k1.y; kn[6]=k1.z; kn[7]=k1.w;
      v0n = hs[vb * 64 + p0];
      v1n = hs[vb * 64 + p0 + 1];
    }

    // ---- B: pred = w2 h + b2 ; d = (2/64)(pred - v)   (all lanes get d)
    float hh[4];
    {
      const float4 h4 = *(const float4*)(h_s + c0);
      hh[0]=h4.x; hh[1]=h4.y; hh[2]=h4.z; hh[3]=h4.w;
    }
    float q0 = 0.f, q1 = 0.f;
#pragma unroll
    for (int ii = 0; ii < 4; ++ii) {
      q0 = fmaf(w2r[ii],     hh[ii], q0);
      q1 = fmaf(w2r[4 + ii], hh[ii], q1);
    }
    q0 += __shfl_xor(q0, 1, 64);  q1 += __shfl_xor(q1, 1, 64);
    q0 += __shfl_xor(q0, 2, 64);  q1 += __shfl_xor(q1, 2, 64);
    q0 += __shfl_xor(q0, 4, 64);  q1 += __shfl_xor(q1, 4, 64);
    const float dd0 = 0.03125f * (q0 + b2v0 - v0);
    const float dd1 = 0.03125f * (q1 + b2v1 - v1);

    // ---- C: dh partials with OLD w2
    float dp[4];
#pragma unroll
    for (int ii = 0; ii < 4; ++ii)
      dp[ii] = fmaf(w2r[4 + ii], dd1, w2r[ii] * dd0);

    // ---- w2/b2 Adam (grad doesn't involve w2; dp already captured old w2)
#pragma unroll
    for (int ii = 0; ii < 4; ++ii) {
      adam_upd(w2r[ii],     m1b[ii],     m2b[ii],     dd0 * hh[ii], c2inv, nls);
      adam_upd(w2r[4 + ii], m1b[4 + ii], m2b[4 + ii], dd1 * hh[ii], c2inv, nls);
    }
    adam_upd(b2v0, m1d0, m2d0, dd0, c2inv, nls);
    adam_upd(b2v1, m1d1, m2d1, dd1, c2inv, nls);

    // ---- C reduce: within-wave over the 8 i1-groups; store transposed
#pragma unroll
    for (int ii = 0; ii < 4; ++ii) {
      dp[ii] += __shfl_xor(dp[ii], 8, 64);
      dp[ii] += __shfl_xor(dp[ii], 16, 64);
      dp[ii] += __shfl_xor(dp[ii], 32, 64);
    }
    if (lane < 8) {
      dhp[4 * lane + 0][wv] = dp[0];
      dhp[4 * lane + 1][wv] = dp[1];
      dhp[4 * lane + 2][wv] = dp[2];
      dhp[4 * lane + 3][wv] = dp[3];
    }
    __syncthreads();

    // ---- D: dh (single b128 read, same pairing as R1) + w1/b1 Adam
    const float4 d4 = *(const float4*)dhp[i1];
    const float dhsum = (d4.x + d4.y) + (d4.z + d4.w);
    const float dh = (hv > 0.f) ? dhsum : 0.f;
#pragma unroll
    for (int jj = 0; jj < 8; ++jj)
      adam_upd(w1r[jj], m1a[jj], m2a[jj], dh * kk[jj], c2inv, nls);
    adam_upd(b1v, m1c, m2c, dh, c2inv, nls);

    // ---- A of next step with prefetched k (w1 grad above used old kk)
    {
#pragma unroll
      for (int jj = 0; jj < 8; ++jj) kk[jj] = kn[jj];
      v0 = v0n; v1 = v1n;
      float pa = 0.f;
#pragma unroll
      for (int jj = 0; jj < 8; ++jj) pa = fmaf(w1r[jj], kk[jj], pa);
      pa += __shfl_xor(pa, 1, 64);
      pa += __shfl_xor(pa, 2, 64);
      pa += __shfl_xor(pa, 4, 64);
      hv = fmaxf(pa + b1v, 0.f);
      if (sub == 1) h_s[i1] = hv;
    }
    nls_c = nls_n;
    c2i_c = c2i_n;
    __syncthreads();
  }

  // ---- epilogue: ctx = w2 h_q + b2 (no relu on output layer)
  {
    float hh[4];
    const float4 h4 = *(const float4*)(h_s + c0);
    hh[0]=h4.x; hh[1]=h4.y; hh[2]=h4.z; hh[3]=h4.w;
    float q0 = 0.f, q1 = 0.f;
#pragma unroll
    for (int ii = 0; ii < 4; ++ii) {
      q0 = fmaf(w2r[ii],     hh[ii], q0);
      q1 = fmaf(w2r[4 + ii], hh[ii], q1);
    }
    q0 += __shfl_xor(q0, 1, 64);  q1 += __shfl_xor(q1, 1, 64);
    q0 += __shfl_xor(q0, 2, 64);  q1 += __shfl_xor(q1, 2, 64);
    q0 += __shfl_xor(q0, 4, 64);  q1 += __shfl_xor(q1, 4, 64);
    if (sub == 2) { ctx[p0] = q0 + b2v0; ctx[p0 + 1] = q1 + b2v1; }
  }
  __syncthreads();

  // ---- output projection: out[b][u] = out_b[u] + sum_p out_w[u][p]*ctx[p]
  if (t < 64) {
    float acc = outb[t];
    const float* wrow = outw + t * 64;
#pragma unroll 8
    for (int p = 0; p < 64; ++p) acc = fmaf(wrow[p], ctx[p], acc);
    out[(long long)b * 64 + t] = acc;
  }
}

extern "C" void kernel_launch(void* const* d_in, const int* in_sizes, int n_in,
                              void* d_out, int out_size, void* d_ws, size_t ws_size,
                              hipStream_t stream) {
  const int*   seq  = (const int*)  d_in[0];
  const float* emb  = (const float*)d_in[1];
  const float* ffw1 = (const float*)d_in[2];
  const float* ffb1 = (const float*)d_in[3];
  const float* ffw2 = (const float*)d_in[4];
  const float* ffb2 = (const float*)d_in[5];
  const float* lng  = (const float*)d_in[6];
  const float* lnb  = (const float*)d_in[7];
  const float* fc1w = (const float*)d_in[8];
  const float* fc1b = (const float*)d_in[9];
  const float* fc2w = (const float*)d_in[10];
  const float* fc2b = (const float*)d_in[11];
  const float* outw = (const float*)d_in[12];
  const float* outb = (const float*)d_in[13];
  float* out    = (float*)d_out;
  float* hs_tab = (float*)d_ws;            // 64*64 floats = 16 KB
  float* tab    = (float*)d_ws + 4096;     // 3069*2 floats (padded to 6144)

  prep_kernel<<<64, 128, 0, stream>>>(emb, ffw1, ffb1, ffw2, ffb2, lng, lnb, hs_tab);
  table_kernel<<<1, 64, 0, stream>>>(tab);
  scan_kernel<<<256, 256, 0, stream>>>(seq, hs_tab, tab, fc1w, fc1b, fc2w, fc2b,
                                       outw, outb, out);
}

// Round 4
// 2582.334 us; speedup vs baseline: 1.2177x; 1.2094x over previous
//
#include <hip/hip_runtime.h>

// ---------------------------------------------------------------------------
// ParamMemAdam: hs features collapse to a 64-entry token table. 256
// independent sequential Adam scans (3069 steps) -> one block per batch
// element, params+moments in regs.
// R4: replace ds_bpermute-based __shfl_xor chains (DS-pipe, ~100cy dependent
// latency, 9 serial stages/step) with DPP VALU cross-lane adds. Bit-identical
// partners: xor1=quad_perm 0xB1, xor2=quad_perm 0x4E, xor4->row_half_mirror
// (same bits after xor1+xor2 by add-commutativity), xor8=row_ror:8,
// xor16=ds_swizzle 0x401F, xor32=ds_bpermute (hoisted index).
// Adam math bit-identical to R1/R3 (validated trajectory).
// ---------------------------------------------------------------------------

template <int CTRL>
__device__ __forceinline__ float dpp_add(float x) {
  union { float f; int i; } u, r;
  u.f = x;
  r.i = __builtin_amdgcn_update_dpp(0, u.i, CTRL, 0xF, 0xF, true);
  return x + r.f;
}

__device__ __forceinline__ float swz16_add(float x) {
  union { float f; int i; } u, r;
  u.f = x;
  r.i = __builtin_amdgcn_ds_swizzle(u.i, 0x401F);  // xor lane^16
  return x + r.f;
}

__device__ __forceinline__ float bp_add(float x, int idx) {
  union { float f; int i; } u, r;
  u.f = x;
  r.i = __builtin_amdgcn_ds_bpermute(idx, u.i);    // idx = (lane^32)<<2
  return x + r.f;
}

// Bit-identical to R1's update.
__device__ __forceinline__ void adam_upd(float& p, float& m1, float& m2,
                                         float g, float c2inv, float nls)
{
  m1 = fmaf(0.9f,  m1, 0.1f   * g);
  m2 = fmaf(0.999f, m2, 0.001f * (g * g));
  float den = __builtin_amdgcn_sqrtf(m2 * c2inv) + 1e-8f;
  p = fmaf(nls * m1, __builtin_amdgcn_rcpf(den), p);
}

// ---- prep: hs_table[v][j] = LN(e_v + FF(e_v)) for the 64 possible tokens ----
__global__ void prep_kernel(const float* __restrict__ emb,
                            const float* __restrict__ ffw1, const float* __restrict__ ffb1,
                            const float* __restrict__ ffw2, const float* __restrict__ ffb2,
                            const float* __restrict__ lng,  const float* __restrict__ lnb,
                            float* __restrict__ hs_out)
{
  const int v = blockIdx.x;   // token id
  const int t = threadIdx.x;  // 128 threads
  __shared__ float e[64];
  __shared__ float r[128];
  if (t < 64) e[t] = emb[v * 64 + t];
  __syncthreads();
  {
    float s = ffb1[t];
    const float* wrow = ffw1 + t * 64;
#pragma unroll 8
    for (int m = 0; m < 64; ++m) s = fmaf(wrow[m], e[m], s);
    r[t] = fmaxf(s, 0.f);
  }
  __syncthreads();
  if (t < 64) {
    float s = ffb2[t];
    const float* wrow = ffw2 + t * 128;
#pragma unroll 8
    for (int o = 0; o < 128; ++o) s = fmaf(wrow[o], r[o], s);
    float x = e[t] + s;
    float mu = x;
    for (int m = 1; m < 64; m <<= 1) mu += __shfl_xor(mu, m, 64);
    mu *= (1.f / 64.f);
    float dv = x - mu;
    float var = dv * dv;
    for (int m = 1; m < 64; m <<= 1) var += __shfl_xor(var, m, 64);
    var *= (1.f / 64.f);
    float hs = dv / sqrtf(var + 1e-5f);
    hs_out[v * 64 + t] = hs * lng[t] + lnb[t];
  }
}

// ---- per-step Adam scale table: EXACT op sequence of the R1 in-loop code ----
__global__ __launch_bounds__(64)
void table_kernel(float* __restrict__ tab)   // tab[2n] = nls, tab[2n+1] = c2inv
{
  if (threadIdx.x != 0) return;
  double pb1 = 1.0, pb2 = 1.0;
  for (int n = 0; n < 3069; ++n) {
    pb1 *= 0.9; pb2 *= 0.999;
    float c1inv = __builtin_amdgcn_rcpf((float)(1.0 - pb1));
    float c2inv = __builtin_amdgcn_rcpf((float)(1.0 - pb2));
    tab[2 * n]     = -0.05f * c1inv;
    tab[2 * n + 1] = c2inv;
  }
}

// ---- main scan: one block per batch element -------------------------------
// thread t: w1 row i1=t>>3, cols j0=(t&7)*8..+8 ; w2 rows p0=2*i1,p0+1,
// cols c0=(t&7)*4..+4. b1[i1], b2[p0..p0+1] replicated across the 8-lane group.
__global__ __launch_bounds__(256)
void scan_kernel(const int* __restrict__ seq, const float* __restrict__ hs_tab,
                 const float* __restrict__ tab_g,
                 const float* __restrict__ fc1w, const float* __restrict__ fc1b,
                 const float* __restrict__ fc2w, const float* __restrict__ fc2b,
                 const float* __restrict__ outw, const float* __restrict__ outb,
                 float* __restrict__ out)
{
  const int b    = blockIdx.x;
  const int t    = threadIdx.x;
  const int lane = t & 63;
  const int wv   = t >> 6;
  const int i1   = t >> 3;
  const int j0   = (t & 7) << 3;
  const int p0   = i1 << 1;
  const int c0   = (t & 7) << 2;
  const int sub  = t & 7;
  const int bp32 = ((lane ^ 32) << 2);   // hoisted ds_bpermute index

  __shared__ __align__(16) float hs[4096];    // token table 64x64
  __shared__ __align__(16) int   sq[2048];    // this batch's token ids
  __shared__ __align__(16) float tabs[6144];  // (nls, c2inv) per step
  __shared__ __align__(16) float h_s[32];     // hidden vector
  __shared__ __align__(16) float dhp[32][4];  // dh partials, [i1][wave]
  __shared__ __align__(16) float ctx[64];     // final context

  for (int i = t; i < 1024; i += 256)
    ((float4*)hs)[i] = ((const float4*)hs_tab)[i];
  {
    const int4* sg = (const int4*)(seq + (long long)b * 2048);
    for (int i = t; i < 512; i += 256) ((int4*)sq)[i] = sg[i];
  }
  for (int i = t; i < 1536; i += 256)
    ((float4*)tabs)[i] = ((const float4*)tab_g)[i];

  float w1r[8], m1a[8], m2a[8];
  float w2r[8], m1b[8], m2b[8];
#pragma unroll
  for (int jj = 0; jj < 8; ++jj) {
    w1r[jj] = fc1w[i1 * 64 + j0 + jj];
    m1a[jj] = 0.f; m2a[jj] = 0.f;
  }
#pragma unroll
  for (int z = 0; z < 8; ++z) {
    w2r[z] = fc2w[(p0 + (z >> 2)) * 32 + c0 + (z & 3)];
    m1b[z] = 0.f; m2b[z] = 0.f;
  }
  float b1v  = fc1b[i1];     float m1c = 0.f, m2c = 0.f;
  float b2v0 = fc2b[p0];     float m1d0 = 0.f, m2d0 = 0.f;
  float b2v1 = fc2b[p0 + 1]; float m1d1 = 0.f, m2d1 = 0.f;

  __syncthreads();

  int jm = 1;

  // ---- prologue: step-0 scales, load (k0,v0), phase A of step 0
  float nls_c  = tabs[0];
  float c2i_c  = tabs[1];
  float kk[8], hv, v0, v1;
  {
    const int ka = sq[0], vb = sq[1];
    const float4 k0 = *(const float4*)(hs + ka * 64 + j0);
    const float4 k1 = *(const float4*)(hs + ka * 64 + j0 + 4);
    kk[0]=k0.x; kk[1]=k0.y; kk[2]=k0.z; kk[3]=k0.w;
    kk[4]=k1.x; kk[5]=k1.y; kk[6]=k1.z; kk[7]=k1.w;
    v0 = hs[vb * 64 + p0];
    v1 = hs[vb * 64 + p0 + 1];
    float pa = 0.f;
#pragma unroll
    for (int jj = 0; jj < 8; ++jj) pa = fmaf(w1r[jj], kk[jj], pa);
    pa = dpp_add<0xB1>(pa);   // xor1
    pa = dpp_add<0x4E>(pa);   // xor2
    pa = dpp_add<0x141>(pa);  // xor4-equivalent (row_half_mirror)
    hv = fmaxf(pa + b1v, 0.f);
    if (sub == 1) h_s[i1] = hv;
  }
  __syncthreads();

  for (int step = 0; step < 3069; ++step) {
    // ---- prefetch next step's scales (uniform LDS broadcast)
    const int ni = (step < 3068) ? (step + 1) : 3068;
    const float nls_n = tabs[2 * ni];
    const float c2i_n = tabs[2 * ni + 1];
    const float nls   = nls_c;
    const float c2inv = c2i_c;

    // ---- prefetch (k,v) for step+1 (or query on last step)
    float kn[8], v0n, v1n;
    {
      int ka, vb;
      if (step < 3068) {
        ka = sq[2 * jm]; vb = sq[2 * jm + 1];
        jm = (jm == 1022) ? 0 : jm + 1;
      } else {
        ka = sq[2047]; vb = 0;  // query token; v unused afterwards
      }
      const float4 k0 = *(const float4*)(hs + ka * 64 + j0);
      const float4 k1 = *(const float4*)(hs + ka * 64 + j0 + 4);
      kn[0]=k0.x; kn[1]=k0.y; kn[2]=k0.z; kn[3]=k0.w;
      kn[4]=k1.x; kn[5]=k1.y; kn[6]=k1.z; kn[7]=k1.w;
      v0n = hs[vb * 64 + p0];
      v1n = hs[vb * 64 + p0 + 1];
    }

    // ---- B: pred = w2 h + b2 ; d = (2/64)(pred - v)   (all lanes get d)
    float hh[4];
    {
      const float4 h4 = *(const float4*)(h_s + c0);
      hh[0]=h4.x; hh[1]=h4.y; hh[2]=h4.z; hh[3]=h4.w;
    }
    float q0 = 0.f, q1 = 0.f;
#pragma unroll
    for (int ii = 0; ii < 4; ++ii) {
      q0 = fmaf(w2r[ii],     hh[ii], q0);
      q1 = fmaf(w2r[4 + ii], hh[ii], q1);
    }
    q0 = dpp_add<0xB1>(q0);   q1 = dpp_add<0xB1>(q1);
    q0 = dpp_add<0x4E>(q0);   q1 = dpp_add<0x4E>(q1);
    q0 = dpp_add<0x141>(q0);  q1 = dpp_add<0x141>(q1);
    const float dd0 = 0.03125f * (q0 + b2v0 - v0);
    const float dd1 = 0.03125f * (q1 + b2v1 - v1);

    // ---- C: dh partials with OLD w2
    float dp[4];
#pragma unroll
    for (int ii = 0; ii < 4; ++ii)
      dp[ii] = fmaf(w2r[4 + ii], dd1, w2r[ii] * dd0);

    // ---- C reduce first (on critical path): xor8 DPP, xor16 swizzle,
    //      xor32 bpermute (DS stages pipeline 4-wide)
#pragma unroll
    for (int ii = 0; ii < 4; ++ii) dp[ii] = dpp_add<0x128>(dp[ii]);  // xor8
#pragma unroll
    for (int ii = 0; ii < 4; ++ii) dp[ii] = swz16_add(dp[ii]);       // xor16
#pragma unroll
    for (int ii = 0; ii < 4; ++ii) dp[ii] = bp_add(dp[ii], bp32);    // xor32
    if (lane < 8) {
      dhp[4 * lane + 0][wv] = dp[0];
      dhp[4 * lane + 1][wv] = dp[1];
      dhp[4 * lane + 2][wv] = dp[2];
      dhp[4 * lane + 3][wv] = dp[3];
    }

    // ---- w2/b2 Adam (off the critical path; overlaps C-reduce DS latency)
#pragma unroll
    for (int ii = 0; ii < 4; ++ii) {
      adam_upd(w2r[ii],     m1b[ii],     m2b[ii],     dd0 * hh[ii], c2inv, nls);
      adam_upd(w2r[4 + ii], m1b[4 + ii], m2b[4 + ii], dd1 * hh[ii], c2inv, nls);
    }
    adam_upd(b2v0, m1d0, m2d0, dd0, c2inv, nls);
    adam_upd(b2v1, m1d1, m2d1, dd1, c2inv, nls);
    __syncthreads();

    // ---- D: dh (single b128 read, same pairing as R1) + w1/b1 Adam
    const float4 d4 = *(const float4*)dhp[i1];
    const float dhsum = (d4.x + d4.y) + (d4.z + d4.w);
    const float dh = (hv > 0.f) ? dhsum : 0.f;
#pragma unroll
    for (int jj = 0; jj < 8; ++jj)
      adam_upd(w1r[jj], m1a[jj], m2a[jj], dh * kk[jj], c2inv, nls);
    adam_upd(b1v, m1c, m2c, dh, c2inv, nls);

    // ---- A of next step with prefetched k (w1 grad above used old kk)
    {
#pragma unroll
      for (int jj = 0; jj < 8; ++jj) kk[jj] = kn[jj];
      v0 = v0n; v1 = v1n;
      float pa = 0.f;
#pragma unroll
      for (int jj = 0; jj < 8; ++jj) pa = fmaf(w1r[jj], kk[jj], pa);
      pa = dpp_add<0xB1>(pa);
      pa = dpp_add<0x4E>(pa);
      pa = dpp_add<0x141>(pa);
      hv = fmaxf(pa + b1v, 0.f);
      if (sub == 1) h_s[i1] = hv;
    }
    nls_c = nls_n;
    c2i_c = c2i_n;
    __syncthreads();
  }

  // ---- epilogue: ctx = w2 h_q + b2 (no relu on output layer)
  {
    float hh[4];
    const float4 h4 = *(const float4*)(h_s + c0);
    hh[0]=h4.x; hh[1]=h4.y; hh[2]=h4.z; hh[3]=h4.w;
    float q0 = 0.f, q1 = 0.f;
#pragma unroll
    for (int ii = 0; ii < 4; ++ii) {
      q0 = fmaf(w2r[ii],     hh[ii], q0);
      q1 = fmaf(w2r[4 + ii], hh[ii], q1);
    }
    q0 = dpp_add<0xB1>(q0);   q1 = dpp_add<0xB1>(q1);
    q0 = dpp_add<0x4E>(q0);   q1 = dpp_add<0x4E>(q1);
    q0 = dpp_add<0x141>(q0);  q1 = dpp_add<0x141>(q1);
    if (sub == 2) { ctx[p0] = q0 + b2v0; ctx[p0 + 1] = q1 + b2v1; }
  }
  __syncthreads();

  // ---- output projection: out[b][u] = out_b[u] + sum_p out_w[u][p]*ctx[p]
  if (t < 64) {
    float acc = outb[t];
    const float* wrow = outw + t * 64;
#pragma unroll 8
    for (int p = 0; p < 64; ++p) acc = fmaf(wrow[p], ctx[p], acc);
    out[(long long)b * 64 + t] = acc;
  }
}

extern "C" void kernel_launch(void* const* d_in, const int* in_sizes, int n_in,
                              void* d_out, int out_size, void* d_ws, size_t ws_size,
                              hipStream_t stream) {
  const int*   seq  = (const int*)  d_in[0];
  const float* emb  = (const float*)d_in[1];
  const float* ffw1 = (const float*)d_in[2];
  const float* ffb1 = (const float*)d_in[3];
  const float* ffw2 = (const float*)d_in[4];
  const float* ffb2 = (const float*)d_in[5];
  const float* lng  = (const float*)d_in[6];
  const float* lnb  = (const float*)d_in[7];
  const float* fc1w = (const float*)d_in[8];
  const float* fc1b = (const float*)d_in[9];
  const float* fc2w = (const float*)d_in[10];
  const float* fc2b = (const float*)d_in[11];
  const float* outw = (const float*)d_in[12];
  const float* outb = (const float*)d_in[13];
  float* out    = (float*)d_out;
  float* hs_tab = (float*)d_ws;            // 64*64 floats = 16 KB
  float* tab    = (float*)d_ws + 4096;     // 3069*2 floats (padded to 6144)

  prep_kernel<<<64, 128, 0, stream>>>(emb, ffw1, ffb1, ffw2, ffb2, lng, lnb, hs_tab);
  table_kernel<<<1, 64, 0, stream>>>(tab);
  scan_kernel<<<256, 256, 0, stream>>>(seq, hs_tab, tab, fc1w, fc1b, fc2w, fc2b,
                                       outw, outb, out);
}